// Round 6
// baseline (228.292 us; speedup 1.0000x reference)
//
#include <hip/hip_runtime.h>
#include <stdint.h>

// Problem constants (match reference)
#define N_Q   50000
#define N_S   100000
#define KNB   32
#define NKP   27
#define CH    64            // IN == OUT == 64
#define KP_EXT 0.057735026918962584f   // 2*0.1/(KP-1)/sqrt(3)
#define BBOX  0.158f                    // 0.1 + KP_EXT + margin
#define NEG_SLOPE 0.01f
#define NPAIR (N_Q * KNB)               // 1,600,000 (divisible by 256)

// ---------------------------------------------------------------------------
// Kernel 0: zero the output, reset the candidate counter.
// ---------------------------------------------------------------------------
__global__ __launch_bounds__(256) void init_kernel(float* __restrict__ out,
                                                   unsigned* __restrict__ counter)
{
    int tid = blockIdx.x * 256 + threadIdx.x;
    if (tid == 0) *counter = 0u;
    float4* o4 = reinterpret_cast<float4*>(out);
    const int n4 = (N_Q * CH) / 4;      // 800,000
    for (int i = tid; i < n4; i += gridDim.x * 256)
        o4[i] = make_float4(0.f, 0.f, 0.f, 0.f);
}

// ---------------------------------------------------------------------------
// Kernel A: thread-per-pair bbox scan. No tail: every thread does identical
// tiny work. Survivors (~0.37%) are ballot-compacted and appended with ONE
// atomic per wave-with-hits (~4-6K atomics total).
// The exact 27-sphere test is deferred to kernel B.
// ---------------------------------------------------------------------------
__global__ __launch_bounds__(256) void scan_kernel(
    const float* __restrict__ q_pts,    // [N_Q,3]
    const float* __restrict__ s_pts,    // [N_S,3]
    const int*   __restrict__ inds,     // [N_Q,KNB] int32 OR int64 (sniffed)
    unsigned* __restrict__ counter,
    unsigned* __restrict__ list,
    unsigned capacity)
{
    const int p = blockIdx.x * 256 + threadIdx.x;   // pair index, always < NPAIR
    const int lane = threadIdx.x & 63;

    // layout sniff: int64 (LE) => high dwords of elems 0..3 are all zero.
    // Uniform addresses -> scalar loads, L2-hot.
    const bool i64 = (inds[1] == 0) & (inds[3] == 0) & (inds[5] == 0) & (inds[7] == 0);

    bool hit = false;
    if (p < NPAIR) {
        int v = i64 ? reinterpret_cast<const int2*>(inds)[p].x : inds[p];
        const int m = N_S + 1;                       // python-style mod (shadow = N_S)
        int idx = v % m; if (idx < 0) idx += m;
        if (idx < N_S) {
            const int n = p >> 5;                    // KNB == 32
            float rx = s_pts[idx * 3 + 0] - q_pts[n * 3 + 0];
            float ry = s_pts[idx * 3 + 1] - q_pts[n * 3 + 1];
            float rz = s_pts[idx * 3 + 2] - q_pts[n * 3 + 2];
            hit = (fabsf(rx) <= BBOX) & (fabsf(ry) <= BBOX) & (fabsf(rz) <= BBOX);
        }
    }

    unsigned long long mask = __ballot(hit);
    if (mask) {
        const int leader = __ffsll((long long)mask) - 1;
        unsigned base = 0u;
        if (lane == leader)
            base = atomicAdd(counter, (unsigned)__popcll(mask));
        base = __shfl(base, leader, 64);
        if (hit) {
            unsigned long long lower = mask & ((1ull << lane) - 1ull);
            unsigned slot = base + (unsigned)__popcll(lower);
            if (slot < capacity) list[slot] = (unsigned)p;
        }
    }
}

// ---------------------------------------------------------------------------
// Kernel B: one wave per candidate pair (grid-stride, ~1 per wave).
//   exact 27-pt test -> (if any) preactivation GEMV + weighted kp_w GEMVs
//   -> atomicAdd into out[n,:].
// ---------------------------------------------------------------------------
__global__ __launch_bounds__(256) void accum_kernel(
    const float* __restrict__ q_pts,
    const float* __restrict__ s_pts,
    const int*   __restrict__ inds,
    const float* __restrict__ x,        // [N_S,CH]
    const float* __restrict__ W_pre,    // [CH,CH]
    const float* __restrict__ b_pre,    // [CH]
    const float* __restrict__ kp_w,     // [NKP,CH,CH]
    const float* __restrict__ kpts,     // [NKP,3]
    const unsigned* __restrict__ counter,
    const unsigned* __restrict__ list,
    unsigned capacity,
    float* __restrict__ out)            // [N_Q,CH]
{
    unsigned cnt = *counter;
    if (cnt > capacity) cnt = capacity;

    const int lane = threadIdx.x & 63;
    const int gw = blockIdx.x * (blockDim.x >> 6) + (threadIdx.x >> 6);
    const int nw = gridDim.x * (blockDim.x >> 6);

    const bool i64 = (inds[1] == 0) & (inds[3] == 0) & (inds[5] == 0) & (inds[7] == 0);
    const float e2 = KP_EXT * KP_EXT;

    for (unsigned h = gw; h < cnt; h += nw) {
        const unsigned p = list[h];
        const int n = (int)(p >> 5);
        int v = i64 ? reinterpret_cast<const int2*>(inds)[p].x : inds[(int)p];
        const int m = N_S + 1;
        int idx = v % m; if (idx < 0) idx += m;      // < N_S guaranteed (bbox passed)

        const float rx = s_pts[idx * 3 + 0] - q_pts[n * 3 + 0];
        const float ry = s_pts[idx * 3 + 1] - q_pts[n * 3 + 1];
        const float rz = s_pts[idx * 3 + 2] - q_pts[n * 3 + 2];

        // exact 27-sphere test first (cheap, wave-uniform data via broadcast)
        unsigned active = 0u;
        #pragma unroll 1
        for (int l = 0; l < NKP; ++l) {
            float dx = rx - kpts[l * 3 + 0];
            float dy = ry - kpts[l * 3 + 1];
            float dz = rz - kpts[l * 3 + 2];
            if (dx * dx + dy * dy + dz * dz < e2) active |= (1u << l);
        }
        if (active == 0u) continue;                  // ~27% of bbox candidates

        // preactivation GEMV: f[lane] = leaky_relu(b + sum_i x[s,i]*W_pre[i,lane])
        float xr = x[(long)idx * CH + lane];
        float f  = b_pre[lane];
        #pragma unroll
        for (int i = 0; i < CH; ++i) {
            float xi = __shfl(xr, i, 64);
            f = fmaf(xi, W_pre[i * CH + lane], f);
        }
        f = (f >= 0.f) ? f : NEG_SLOPE * f;

        // weighted conv over active kernel points (<=2 typically)
        float acc = 0.f;
        unsigned am = active;
        while (am) {
            int l = __ffs(am) - 1;
            am &= am - 1;
            float dx = rx - kpts[l * 3 + 0];
            float dy = ry - kpts[l * 3 + 1];
            float dz = rz - kpts[l * 3 + 2];
            float d2 = dx * dx + dy * dy + dz * dz;
            float w = 1.f - sqrtf(d2) / KP_EXT;      // > 0 here
            const float* Wl = kp_w + (long)l * CH * CH;
            float partial = 0.f;
            #pragma unroll
            for (int i = 0; i < CH; ++i) {
                float fi = __shfl(f, i, 64);
                partial = fmaf(fi, Wl[i * CH + lane], partial);
            }
            acc = fmaf(w, partial, acc);
        }
        atomicAdd(&out[(long)n * CH + lane], acc);
    }
}

// ---------------------------------------------------------------------------
extern "C" void kernel_launch(void* const* d_in, const int* in_sizes, int n_in,
                              void* d_out, int out_size, void* d_ws, size_t ws_size,
                              hipStream_t stream)
{
    const float* q_pts = (const float*)d_in[0];
    const float* s_pts = (const float*)d_in[1];
    const int*   inds  = (const int*)  d_in[2];
    const float* x     = (const float*)d_in[3];
    const float* W_pre = (const float*)d_in[4];
    const float* b_pre = (const float*)d_in[5];
    const float* kp_w  = (const float*)d_in[6];
    const float* kpts  = (const float*)d_in[7];
    float* out = (float*)d_out;

    // workspace: [0,128) counter, [128,...) candidate list (u32)
    unsigned* counter = (unsigned*)d_ws;
    unsigned* list    = (unsigned*)((char*)d_ws + 128);
    size_t cap = (ws_size > 128) ? (ws_size - 128) / 4 : 0;
    if (cap > 2000000) cap = 2000000;
    unsigned capacity = (unsigned)cap;

    // 0: zero output + counter  (12.8 MB)
    init_kernel<<<2048, 256, 0, stream>>>(out, counter);

    // A: bbox scan, thread per pair (6250 blocks, no tail)
    scan_kernel<<<NPAIR / 256, 256, 0, stream>>>(q_pts, s_pts, inds,
                                                 counter, list, capacity);

    // B: one wave per candidate (~6K candidates over 4096 waves)
    accum_kernel<<<256, 256, 0, stream>>>(q_pts, s_pts, inds, x, W_pre, b_pre,
                                          kp_w, kpts, counter, list, capacity, out);
}

// Round 10
// 160.872 us; speedup vs baseline: 1.4191x; 1.4191x over previous
//
#include <hip/hip_runtime.h>
#include <stdint.h>

// Problem constants (match reference)
#define N_Q   50000
#define N_S   100000
#define KNB   32
#define NKP   27
#define CH    64            // IN == OUT == 64
#define KP_EXT 0.057735026918962584f   // 2*0.1/(KP-1)/sqrt(3)
#define BBOX  0.158f                    // 0.1 + KP_EXT + margin
#define NEG_SLOPE 0.01f

// ---------------------------------------------------------------------------
// Fused sparse KPConv, one wave per 2 queries (64 pairs -> 64 lanes).
//
// r6 evidence: per-hit processing via 64-step __shfl-broadcast GEMVs costs
// ~15 us/hit (each shfl = ~120cy LDS round trip on a serial fma chain) and
// waves queued ~5.5 hits serially -> 88 us. Fix:
//   - lane = OUTPUT-channel layout for both GEMVs; the gathered x-row is
//     staged once into a per-wave LDS slot, then all inner-loop operands are
//     independent (prefetchable) LDS/global reads. Zero shuffles in the
//     inner loops; serial dependence = 64 fma (~256 cy).
//   - one wave handles only its own 2 queries' hits (~0.17 avg, tiny tail).
//   - no workspace, no atomics, no init kernel: out rows written exactly once.
// ---------------------------------------------------------------------------
__global__ __launch_bounds__(256) void kpconv_kernel(
    const float* __restrict__ q_pts,    // [N_Q,3]
    const float* __restrict__ s_pts,    // [N_S,3]
    const int*   __restrict__ inds,     // [N_Q,KNB] int32 OR int64 (sniffed)
    const float* __restrict__ x,        // [N_S,CH]
    const float* __restrict__ W_pre,    // [CH,CH]
    const float* __restrict__ b_pre,    // [CH]
    const float* __restrict__ kp_w,     // [NKP,CH,CH]
    const float* __restrict__ kpts,     // [NKP,3]
    float* __restrict__ out)            // [N_Q,CH]
{
    __shared__ float sW[CH * CH];       // 16 KB, W_pre row-major [i][o]
    __shared__ float sB[CH];
    __shared__ float sKP[NKP * 3];
    __shared__ float lf[4][CH];         // per-wave staging (x-row, then f)

    for (int i = threadIdx.x; i < CH * CH; i += 256) sW[i] = W_pre[i];
    if (threadIdx.x < CH)      sB[threadIdx.x]  = b_pre[threadIdx.x];
    if (threadIdx.x < NKP * 3) sKP[threadIdx.x] = kpts[threadIdx.x];
    __syncthreads();

    const int lane = threadIdx.x & 63;
    const int wid  = threadIdx.x >> 6;
    const int job  = blockIdx.x * 4 + wid;     // 2 queries per job; 25000 jobs

    // layout sniff: int64 (LE) => high dwords of elems 0..3 are all zero.
    // For genuine random int32 indices P(all four == 0) ~ 1e-20.
    const bool i64 = (inds[1] == 0) & (inds[3] == 0) & (inds[5] == 0) & (inds[7] == 0);
    const float e2 = KP_EXT * KP_EXT;

    // ---- scan: 64 lanes = 2 queries x 32 neighbors ----
    const long fp = (long)job * 64 + lane;
    const int  v  = i64 ? reinterpret_cast<const int2*>(inds)[fp].x : inds[fp];

    const int  q  = job * 2 + (lane >> 5);
    const float qx = q_pts[q * 3 + 0];
    const float qy = q_pts[q * 3 + 1];
    const float qz = q_pts[q * 3 + 2];

    const int m_ = N_S + 1;                     // python-style mod (shadow = N_S)
    int idx = v % m_; if (idx < 0) idx += m_;

    float rx = 0.f, ry = 0.f, rz = 0.f;
    bool hit = false;
    if (idx < N_S) {
        rx = s_pts[idx * 3 + 0] - qx;
        ry = s_pts[idx * 3 + 1] - qy;
        rz = s_pts[idx * 3 + 2] - qz;
        if (fabsf(rx) <= BBOX && fabsf(ry) <= BBOX && fabsf(rz) <= BBOX) {
            #pragma unroll 1
            for (int l = 0; l < NKP; ++l) {
                float dx = rx - sKP[l * 3 + 0];
                float dy = ry - sKP[l * 3 + 1];
                float dz = rz - sKP[l * 3 + 2];
                if (dx * dx + dy * dy + dz * dz < e2) { hit = true; break; }
            }
        }
    }

    unsigned long long mask = __ballot(hit);

    float acc0 = 0.f, acc1 = 0.f;

    // ---- per-hit accumulation (lane = output channel; no inner shuffles) ----
    while (mask) {
        const int src = __ffsll((long long)mask) - 1;
        mask &= mask - 1;

        const int   sidx = __shfl(idx, src, 64);
        const float rxs  = __shfl(rx, src, 64);
        const float rys  = __shfl(ry, src, 64);
        const float rzs  = __shfl(rz, src, 64);

        // stage source feature row into this wave's LDS slot (coalesced 256 B)
        lf[wid][lane] = x[(long)sidx * CH + lane];

        // preactivation GEMV: t[o] = b[o] + sum_i x[i] * W_pre[i][o]
        // (same-wave ds_write -> ds_read; compiler orders via lgkmcnt)
        float t = sB[lane];
        #pragma unroll
        for (int i = 0; i < CH; ++i)
            t = fmaf(lf[wid][i], sW[i * CH + lane], t);
        float f = (t >= 0.f) ? t : NEG_SLOPE * t;

        // republish f through the same slot for the conv GEMV
        lf[wid][lane] = f;

        // conv over active kernel points (wave-uniform; <=2 typically)
        #pragma unroll 1
        for (int l = 0; l < NKP; ++l) {
            float dx = rxs - sKP[l * 3 + 0];
            float dy = rys - sKP[l * 3 + 1];
            float dz = rzs - sKP[l * 3 + 2];
            float d2 = dx * dx + dy * dy + dz * dz;
            if (d2 < e2) {
                float w = 1.f - sqrtf(d2) / KP_EXT;    // > 0 here
                const float* Wl = kp_w + (unsigned)(l * CH * CH);
                float partial = 0.f;
                #pragma unroll
                for (int i = 0; i < CH; ++i)
                    partial = fmaf(lf[wid][i], Wl[i * CH + lane], partial);
                if (src < 32) acc0 = fmaf(w, partial, acc0);
                else          acc1 = fmaf(w, partial, acc1);
            }
        }
    }

    // each wave owns exactly queries 2*job and 2*job+1 -> plain stores
    out[((long)job * 2 + 0) * CH + lane] = acc0;
    out[((long)job * 2 + 1) * CH + lane] = acc1;
}

// ---------------------------------------------------------------------------
extern "C" void kernel_launch(void* const* d_in, const int* in_sizes, int n_in,
                              void* d_out, int out_size, void* d_ws, size_t ws_size,
                              hipStream_t stream)
{
    const float* q_pts = (const float*)d_in[0];
    const float* s_pts = (const float*)d_in[1];
    const int*   inds  = (const int*)  d_in[2];
    const float* x     = (const float*)d_in[3];
    const float* W_pre = (const float*)d_in[4];
    const float* b_pre = (const float*)d_in[5];
    const float* kp_w  = (const float*)d_in[6];
    const float* kpts  = (const float*)d_in[7];
    float* out = (float*)d_out;

    // 25000 jobs (2 queries each), 4 waves/block -> 6250 blocks, exact cover
    kpconv_kernel<<<6250, 256, 0, stream>>>(q_pts, s_pts, inds, x,
                                            W_pre, b_pre, kp_w, kpts, out);
}

// Round 13
// 148.295 us; speedup vs baseline: 1.5394x; 1.0848x over previous
//
#include <hip/hip_runtime.h>
#include <stdint.h>

// Problem constants (match reference)
#define N_Q   50000
#define N_S   100000
#define KNB   32
#define NKP   27
#define CH    64            // IN == OUT == 64
#define KP_EXT 0.057735026918962584f   // 2*0.1/(KP-1)/sqrt(3)
#define BBOX  0.158f                    // 0.1 + KP_EXT + margin
#define NEG_SLOPE 0.01f
#define QSCALE 500.0f                   // quantization: 0.002 resolution
#define QTH    81                       // |du|<=81 conservative bbox in units

// ---------------------------------------------------------------------------
// Pack kernel: s_pts -> one dword per point (3 x 10-bit quantized coords).
// Turns the per-pair gather from 3 scattered dwords into 1 (r10 evidence:
// scattered-request occupancy, not BW or shuffles, is the bottleneck).
// ---------------------------------------------------------------------------
__global__ __launch_bounds__(256) void pack_kernel(const float* __restrict__ s_pts,
                                                   uint32_t* __restrict__ packed)
{
    int i = blockIdx.x * 256 + threadIdx.x;
    if (i >= N_S) return;
    float px = s_pts[i * 3 + 0];
    float py = s_pts[i * 3 + 1];
    float pz = s_pts[i * 3 + 2];
    uint32_t ux = (uint32_t)fminf(fmaxf(px * QSCALE, 0.f), 1023.f);
    uint32_t uy = (uint32_t)fminf(fmaxf(py * QSCALE, 0.f), 1023.f);
    uint32_t uz = (uint32_t)fminf(fmaxf(pz * QSCALE, 0.f), 1023.f);
    packed[i] = ux | (uy << 10) | (uz << 20);
}

// ---------------------------------------------------------------------------
// Fused sparse KPConv, one wave per 2 queries (64 pairs -> 64 lanes).
//   - ONE packed-dword gather per pair; integer bbox test (conservative:
//     sphere-hit => |r|<=0.1577 => |du|<=80 < QTH, so zero false rejects).
//   - ~0.4% survivors load float s_pts (few active lanes -> few transactions)
//     and run the exact 27-sphere test.
//   - hit path (~4300 total): x-row staged in per-wave LDS slot; lane=output
//     GEMVs against W_pre / kp_w read coalesced from global (L2-hot 16KB
//     panels). No shuffles in inner loops (r10 fix, kept).
//   - NO block LDS staging, NO __syncthreads: minimal wave prologue.
// ---------------------------------------------------------------------------
template<bool PACKED>
__global__ __launch_bounds__(256) void kpconv_kernel(
    const float* __restrict__ q_pts,    // [N_Q,3]
    const float* __restrict__ s_pts,    // [N_S,3]
    const int*   __restrict__ inds,     // [N_Q,KNB] int32 OR int64 (sniffed)
    const float* __restrict__ x,        // [N_S,CH]
    const float* __restrict__ W_pre,    // [CH,CH]
    const float* __restrict__ b_pre,    // [CH]
    const float* __restrict__ kp_w,     // [NKP,CH,CH]
    const float* __restrict__ kpts,     // [NKP,3]
    const uint32_t* __restrict__ packed,// [N_S] quantized coords (if PACKED)
    float* __restrict__ out)            // [N_Q,CH]
{
    __shared__ float lf[4][CH];         // per-wave staging (x-row, then f)

    const int lane = threadIdx.x & 63;
    const int wid  = threadIdx.x >> 6;
    const int job  = blockIdx.x * 4 + wid;     // 2 queries per job; 25000 jobs

    // layout sniff: int64 (LE) => high dwords of elems 0..3 are all zero.
    const bool i64 = (inds[1] == 0) & (inds[3] == 0) & (inds[5] == 0) & (inds[7] == 0);
    const float e2 = KP_EXT * KP_EXT;

    // ---- scan: 64 lanes = 2 queries x 32 neighbors ----
    const long fp = (long)job * 64 + lane;
    const int  v  = i64 ? reinterpret_cast<const int2*>(inds)[fp].x : inds[fp];

    const int  q  = job * 2 + (lane >> 5);
    const float qx = q_pts[q * 3 + 0];
    const float qy = q_pts[q * 3 + 1];
    const float qz = q_pts[q * 3 + 2];

    const int m_ = N_S + 1;                     // python-style mod (shadow = N_S)
    int idx = v % m_; if (idx < 0) idx += m_;

    // ---- cheap candidate test: ONE gathered dword (the hot path) ----
    bool cand = false;
    if (idx < N_S) {
        if (PACKED) {
            uint32_t pk = packed[idx];
            int dux = (int)(pk & 1023u)         - (int)(qx * QSCALE);
            int duy = (int)((pk >> 10) & 1023u) - (int)(qy * QSCALE);
            int duz = (int)(pk >> 20)           - (int)(qz * QSCALE);
            cand = (abs(dux) <= QTH) & (abs(duy) <= QTH) & (abs(duz) <= QTH);
        } else {
            cand = true;
        }
    }

    // ---- exact test for the ~0.4% survivors ----
    float rx = 0.f, ry = 0.f, rz = 0.f;
    bool hit = false;
    if (cand) {
        rx = s_pts[idx * 3 + 0] - qx;
        ry = s_pts[idx * 3 + 1] - qy;
        rz = s_pts[idx * 3 + 2] - qz;
        if (fabsf(rx) <= BBOX && fabsf(ry) <= BBOX && fabsf(rz) <= BBOX) {
            #pragma unroll 1
            for (int l = 0; l < NKP; ++l) {
                float dx = rx - kpts[l * 3 + 0];
                float dy = ry - kpts[l * 3 + 1];
                float dz = rz - kpts[l * 3 + 2];
                if (dx * dx + dy * dy + dz * dz < e2) { hit = true; break; }
            }
        }
    }

    unsigned long long mask = __ballot(hit);

    float acc0 = 0.f, acc1 = 0.f;

    // ---- per-hit accumulation (lane = output channel; no inner shuffles) ----
    while (mask) {
        const int src = __ffsll((long long)mask) - 1;
        mask &= mask - 1;

        const int   sidx = __shfl(idx, src, 64);
        const float rxs  = __shfl(rx, src, 64);
        const float rys  = __shfl(ry, src, 64);
        const float rzs  = __shfl(rz, src, 64);

        // stage source feature row into this wave's LDS slot (coalesced 256 B)
        lf[wid][lane] = x[(long)sidx * CH + lane];

        // preactivation GEMV: t[o] = b[o] + sum_i x[i] * W_pre[i][o]
        // W_pre read coalesced from global (16KB panel, L2-hot across hits)
        float t = b_pre[lane];
        #pragma unroll
        for (int i = 0; i < CH; ++i)
            t = fmaf(lf[wid][i], W_pre[i * CH + lane], t);
        float f = (t >= 0.f) ? t : NEG_SLOPE * t;

        // republish f through the same slot for the conv GEMV
        lf[wid][lane] = f;

        // conv over active kernel points (wave-uniform; <=2 typically)
        #pragma unroll 1
        for (int l = 0; l < NKP; ++l) {
            float dx = rxs - kpts[l * 3 + 0];
            float dy = rys - kpts[l * 3 + 1];
            float dz = rzs - kpts[l * 3 + 2];
            float d2 = dx * dx + dy * dy + dz * dz;
            if (d2 < e2) {
                float w = 1.f - sqrtf(d2) / KP_EXT;    // > 0 here
                const float* Wl = kp_w + (unsigned)(l * CH * CH);
                float partial = 0.f;
                #pragma unroll
                for (int i = 0; i < CH; ++i)
                    partial = fmaf(lf[wid][i], Wl[i * CH + lane], partial);
                if (src < 32) acc0 = fmaf(w, partial, acc0);
                else          acc1 = fmaf(w, partial, acc1);
            }
        }
    }

    // each wave owns exactly queries 2*job and 2*job+1 -> plain stores
    out[((long)job * 2 + 0) * CH + lane] = acc0;
    out[((long)job * 2 + 1) * CH + lane] = acc1;
}

// ---------------------------------------------------------------------------
extern "C" void kernel_launch(void* const* d_in, const int* in_sizes, int n_in,
                              void* d_out, int out_size, void* d_ws, size_t ws_size,
                              hipStream_t stream)
{
    const float* q_pts = (const float*)d_in[0];
    const float* s_pts = (const float*)d_in[1];
    const int*   inds  = (const int*)  d_in[2];
    const float* x     = (const float*)d_in[3];
    const float* W_pre = (const float*)d_in[4];
    const float* b_pre = (const float*)d_in[5];
    const float* kp_w  = (const float*)d_in[6];
    const float* kpts  = (const float*)d_in[7];
    float* out = (float*)d_out;

    const bool use_packed = ws_size >= (size_t)N_S * sizeof(uint32_t);
    uint32_t* packed = (uint32_t*)d_ws;

    if (use_packed) {
        pack_kernel<<<(N_S + 255) / 256, 256, 0, stream>>>(s_pts, packed);
        kpconv_kernel<true><<<6250, 256, 0, stream>>>(q_pts, s_pts, inds, x,
                                                      W_pre, b_pre, kp_w, kpts,
                                                      packed, out);
    } else {
        kpconv_kernel<false><<<6250, 256, 0, stream>>>(q_pts, s_pts, inds, x,
                                                       W_pre, b_pre, kp_w, kpts,
                                                       nullptr, out);
    }
}